// Round 9
// baseline (112.257 us; speedup 1.0000x reference)
//
#include <hip/hip_runtime.h>
#include <hip/hip_bf16.h>
#include <math.h>

#define NN 4096
#define EE 65536
#define HH 128
#define RR 32
#define MAXZ 128
#define CUT 4.5f
#define PI_OVER_CUT 0.6981317007977318f
#define LN_EPS 1e-5f

typedef unsigned short u16;
typedef unsigned int u32;
typedef unsigned char u8;
typedef _Float16 h2 __attribute__((ext_vector_type(2)));
typedef _Float16 hf8 __attribute__((ext_vector_type(8)));
typedef float f32x4 __attribute__((ext_vector_type(4)));

__device__ __forceinline__ float dot4(float4 a, float4 b){
    return a.x*b.x + a.y*b.y + a.z*b.z + a.w*b.w;
}
__device__ __forceinline__ float silu(float x){ return x / (1.f + __expf(-x)); }
__device__ __forceinline__ u32 packh2(float a, float b){
    union{u32 u; h2 h;} v; v.h = (h2){(_Float16)a, (_Float16)b}; return v.u;
}
__device__ __forceinline__ float fdot2u(u32 a, u32 b, float c){
    union{u32 u; h2 h;} x, y; x.u = a; y.u = b;
    return __builtin_amdgcn_fdot2(x.h, y.h, c, false);
}
__device__ __forceinline__ u16 f2h(float f){
    union{u16 u; _Float16 h;} v; v.h = (_Float16)f; return v.u;
}
__device__ __forceinline__ float h2f(u16 u){
    union{u16 u_; _Float16 h;} v; v.u_ = u; return (float)v.h;
}

// ---------------- diagnostic signal (f32) ----------------
__global__ void k_sig(float* __restrict__ out, float val, int n){
    int i = blockIdx.x*256 + threadIdx.x;
    if (i < n) out[i] = val;
}

// ---------------- zero deg ----------------
__global__ void k_zero(int* __restrict__ deg){
    deg[blockIdx.x*256 + threadIdx.x] = 0;
}

// ---------------- convert+histogram (512) + Pz GEMM (64) + label vecs (1) ----------------
__global__ __launch_bounds__(256) void k_cvt(const u8* __restrict__ zr,
                                             const u8* __restrict__ eir,
                                             const u8* __restrict__ mr,
                                             int* __restrict__ z32,
                                             int* __restrict__ ei32,
                                             int* __restrict__ m32,
                                             int* __restrict__ deg,
                                             const float* __restrict__ emb_w,
                                             const float* __restrict__ emb2_w,
                                             const float* __restrict__ label_emb_w,
                                             const float* __restrict__ label_emb_b,
                                             const float* __restrict__ mask_token,
                                             const float* __restrict__ label_emb2_w,
                                             const float* __restrict__ label_emb2_b,
                                             const float* __restrict__ emb2_b,
                                             float* __restrict__ PzA,
                                             float* __restrict__ PzB,
                                             float* __restrict__ vecs){
    int b = blockIdx.x, t = threadIdx.x;
    if (b < 512){
        __shared__ int sF1, sF3, sOdd, sZ64, sE64;
        if (t == 0){ sF1=0; sF3=0; sOdd=0; sZ64=1; sE64=1; }
        __syncthreads();
        for (int i = t; i < 4096; i += 256){
            u8 bb = mr[i];
            if ((i & 3) == 1 && bb == 0x3F) sF1 = 1;
            if ((i & 3) == 3 && bb == 0x3F) sF3 = 1;
            if ((i & 3) != 0 && bb != 0)    sOdd = 1;
        }
        const u32* zw = (const u32*)zr;
        const u32* ew = (const u32*)eir;
        for (int i = t; i < 128; i += 256) if (zw[2*i + 1]) sZ64 = 0;
        for (int i = t; i < 512; i += 256) if (ew[2*i + 1]) sE64 = 0;
        __syncthreads();
        int mf = sF1 ? 2 : (sF3 ? 0 : (sOdd ? 1 : 0));
        int z64 = sZ64, e64 = sE64;

        int i = b*256 + t;
        if (i < NN){
            z32[i] = z64 ? ((const int*)zr)[2*i] : ((const int*)zr)[i];
            int mm;
            if (mf == 1)      mm = (mr[i] != 0);
            else if (mf == 2) mm = (((const u16*)mr)[i] != 0);
            else              mm = (((const u32*)mr)[i] != 0u);
            m32[i] = mm;
        }
        if (i < 2*EE){
            int v = e64 ? ((const int*)eir)[2*i] : ((const int*)eir)[i];
            ei32[i] = v;
            if (i < EE) atomicAdd(&deg[v], 1);
        }
        return;
    }
    if (b < 576){
        int zi = (b - 512)*2 + (t >> 7), h = t & 127;
        __shared__ float Zs[2][HH];
        Zs[t >> 7][h] = emb_w[zi*HH + h];
        __syncthreads();
        const float4* wa = (const float4*)(emb2_w + h*2*HH);
        const float4* wb = (const float4*)(emb2_w + h*2*HH + HH);
        float pa = 0.f, pbv = 0.f;
        const float* Z = Zs[t >> 7];
        #pragma unroll 8
        for (int j = 0; j < HH/4; ++j){
            float4 zp = *(const float4*)&Z[4*j];
            pa  += dot4(wa[j], zp);
            pbv += dot4(wb[j], zp);
        }
        PzA[zi*HH + h] = pa;
        PzB[zi*HH + h] = pbv;
        return;
    }
    if (t < 128){
        int h = t;
        const float* wa = label_emb2_w + h*2*HH;
        const float* wb = wa + HH;
        float uA=0.f,vA=0.f,wA=0.f,uB=0.f,vB=0.f,wB=0.f;
        for (int j = 0; j < HH; ++j){
            float a = wa[j], bb = wb[j];
            float u = label_emb_w[j], v = label_emb_b[j], m = mask_token[j];
            uA += a*u; vA += a*v; wA += a*m;
            uB += bb*u; vB += bb*v; wB += bb*m;
        }
        float bias = emb2_b[h] + label_emb2_b[h];
        vecs[0*HH + h] = uA;
        vecs[1*HH + h] = vA + bias;
        vecs[2*HH + h] = wA + bias;
        vecs[3*HH + h] = uB;
        vecs[4*HH + h] = vB;
        vecs[5*HH + h] = wB;
    }
}

// ---------------- block scan of degrees ----------------
__global__ __launch_bounds__(256) void k_scan(const int* __restrict__ deg,
                                              int* __restrict__ offsets,
                                              int* __restrict__ cursor){
    int t = threadIdx.x;
    int lane = t & 63, wid = t >> 6;
    int4 d[4];
    #pragma unroll
    for (int q = 0; q < 4; ++q) d[q] = ((const int4*)deg)[t*4 + q];
    int vals[16];
    #pragma unroll
    for (int q = 0; q < 4; ++q){
        vals[4*q+0]=d[q].x; vals[4*q+1]=d[q].y; vals[4*q+2]=d[q].z; vals[4*q+3]=d[q].w;
    }
    int sum = 0;
    #pragma unroll
    for (int q = 0; q < 16; ++q) sum += vals[q];
    int incl = sum;
    #pragma unroll
    for (int dd = 1; dd < 64; dd <<= 1){ int s = __shfl_up(incl, dd); if (lane >= dd) incl += s; }
    __shared__ int wsum[4];
    if (lane == 63) wsum[wid] = incl;
    __syncthreads();
    int base = 0;
    for (int w = 0; w < wid; ++w) base += wsum[w];
    int run = base + incl - sum;
    #pragma unroll
    for (int q = 0; q < 16; ++q){
        offsets[t*16 + q] = run;
        cursor [t*16 + q] = run;
        run += vals[q];
    }
    if (t == 255) offsets[NN] = run;
}

// ---------------- fused: scatter+edge-meta (256) + weight casts (728) + combine (2048) ----------------
__global__ __launch_bounds__(256) void k_sp(
    const int* __restrict__ ei, int* __restrict__ cursor,
    const float* __restrict__ ew, const float* __restrict__ ev,
    const float* __restrict__ ea,
    u32* __restrict__ attrSh, int* __restrict__ dstA, float4* __restrict__ metaA,
    const float* __restrict__ ls1_w, const float* __restrict__ ls2_w,
    const float* __restrict__ lt0_w, const float* __restrict__ lt1_w,
    const float* __restrict__ lt2_w,
    const float* __restrict__ dp1_w, const float* __restrict__ dp2_w,
    const float* __restrict__ dp3_w,
    u16* __restrict__ ls1H, u16* __restrict__ ls2H, u16* __restrict__ ltH,
    u32* __restrict__ dpTh,
    const int* __restrict__ z32, const int* __restrict__ m32,
    const float* __restrict__ labels,
    const float* __restrict__ PzA, const float* __restrict__ PzB,
    const float* __restrict__ vecs,
    float* __restrict__ Pa, u16* __restrict__ Pbh)
{
    int b = blockIdx.x, t = threadIdx.x;
    if (b < 256){
        int e = b*256 + t;
        int s = ei[e];
        int p = atomicAdd(&cursor[s], 1);
        float d = ew[e];
        float cutv = (d < CUT) ? 0.5f*(__cosf(d*PI_OVER_CUT) + 1.f) : 0.f;
        dstA[p] = ei[EE + e];
        metaA[p] = make_float4(cutv, ev[3*e], ev[3*e+1], ev[3*e+2]);
        const float* a = ea + (size_t)e*RR;
        u32* o = attrSh + (size_t)p*16;
        #pragma unroll
        for (int q = 0; q < 16; ++q)
            o[q] = packh2(cutv*a[2*q], cutv*a[2*q+1]);
        return;
    }
    int pb = b - 256;
    if (pb < 728){
        int i = pb*256 + t;
        if (i < 32768){ ls1H[i] = f2h(ls1_w[i]); return; }
        i -= 32768;
        if (i < 98304){ ls2H[i] = f2h(ls2_w[i]); return; }
        i -= 98304;
        if (i < 16384){ ltH[0*16384 + i] = f2h(lt0_w[i]); return; }
        i -= 16384;
        if (i < 16384){ ltH[1*16384 + i] = f2h(lt1_w[i]); return; }
        i -= 16384;
        if (i < 16384){ ltH[2*16384 + i] = f2h(lt2_w[i]); return; }
        i -= 16384;
        if (i < 6144){
            int j = i >> 11, rem = i & 2047, q = rem >> 7, h = rem & 127;
            const float* src = (j == 0) ? dp1_w : ((j == 1) ? dp2_w : dp3_w);
            dpTh[(j*16 + q)*HH + h] = packh2(src[h*RR + 2*q], src[h*RR + 2*q + 1]);
            return;
        }
        return;
    }
    // ---- combine into Pa (f32) / Pbh (fp16): 2048 blocks ----
    int i = (b - 984)*256 + t;
    int n = i >> 7, h = i & 127;
    int zi = z32[n];
    int mk = m32[n];
    float lab = labels[n];
    float la = mk ? vecs[2*HH + h] : lab*vecs[0*HH + h] + vecs[1*HH + h];
    float lb = mk ? vecs[5*HH + h] : lab*vecs[3*HH + h] + vecs[4*HH + h];
    Pa[i]  = PzA[zi*HH + h] + la;
    Pbh[i] = f2h(PzB[zi*HH + h] + lb);
}

// ---------------- fused gather + tail: per-node gather (LDS-staged X) + LN + MLP + mixing + compose ----------------
// Block b owns nodes 16b..16b+15: gather outputs stay in LDS (Yl staged with the
// tail's tile-row layout), removing the X0/X1/X2/norm2 global round-trip and the
// kernel boundary. Dependency is block-local -> no fences/elections needed.
__global__ __launch_bounds__(512) void k_gt(
    const u32* __restrict__ attrSh, const int* __restrict__ dstA,
    const float4* __restrict__ metaA,
    const u32* __restrict__ dpTh,
    const float* __restrict__ dp1_b, const float* __restrict__ dp2_b,
    const float* __restrict__ dp3_b,
    const float* __restrict__ Pa, const u16* __restrict__ Pbh,
    const int* __restrict__ offsets,
    const float* __restrict__ ln_g, const float* __restrict__ ln_b,
    const u16* __restrict__ ls1H, const float* __restrict__ ls1_b,
    const u16* __restrict__ ls2H, const float* __restrict__ ls2_b,
    float* __restrict__ gates, const u16* __restrict__ ltH,
    float* __restrict__ out)
{
    int n0 = blockIdx.x * 16;
    int t = threadIdx.x;
    int wave = t >> 6, lane = t & 63;
    int rlo = lane & 15, kb = lane >> 4;
    __shared__ u16 Yl[160*136];          // X staging, later mixing-GEMM output
    __shared__ u16 ysH[16][136];
    __shared__ u16 usH[16][264];
    __shared__ float norm2l[16][128];

    // ================= gather phase: 4 groups x 4 nodes =================
    {
        int h = t & 127;
        int g = t >> 7;                  // 0..3
        u32 w1[16], w2[16], w3[16];
        #pragma unroll
        for (int q = 0; q < 16; ++q){
            w1[q] = dpTh[(0*16 + q)*HH + h];
            w2[q] = dpTh[(1*16 + q)*HH + h];
            w3[q] = dpTh[(2*16 + q)*HH + h];
        }
        float fb1 = dp1_b[h], fb2 = dp2_b[h], fb3 = dp3_b[h];
        for (int it = 0; it < 4; ++it){
            int ni = g*4 + it;
            int n = n0 + ni;
            float pa = Pa[n*HH + h];
            float ai = 0.f, aw0 = 0.f, aw1 = 0.f, aw2 = 0.f;
            float m00 = 0.f, m01 = 0.f, m02 = 0.f, m11 = 0.f, m12 = 0.f, m22 = 0.f;

            int e0 = offsets[n], e1 = offsets[n+1];
            int j = e0;
            for (; j + 1 < e1; j += 2){
                int dsta = dstA[j], dstb = dstA[j+1];
                float4 ma = metaA[j], mb = metaA[j+1];
                float sa = pa + h2f(Pbh[(size_t)dsta*HH + h]);
                float sb = pa + h2f(Pbh[(size_t)dstb*HH + h]);
                const u32* Aa = attrSh + (size_t)j*16;
                const u32* Ab = Aa + 16;
                float f1a = ma.x*fb1, f2a = ma.x*fb2, f3a = ma.x*fb3;
                float f1b = mb.x*fb1, f2b = mb.x*fb2, f3b = mb.x*fb3;
                #pragma unroll
                for (int q = 0; q < 16; ++q){
                    u32 a = Aa[q], bq = Ab[q];
                    f1a = fdot2u(a, w1[q], f1a);
                    f2a = fdot2u(a, w2[q], f2a);
                    f3a = fdot2u(a, w3[q], f3a);
                    f1b = fdot2u(bq, w1[q], f1b);
                    f2b = fdot2u(bq, w2[q], f2b);
                    f3b = fdot2u(bq, w3[q], f3b);
                }
                float aa = f1a*sa, ba = f2a*sa, ca = f3a*sa;
                float ab = f1b*sb, bb = f2b*sb, cb = f3b*sb;
                ai  += aa;            ai  += ab;
                aw0 += ba*ma.y;       aw0 += bb*mb.y;
                aw1 += ba*ma.z;       aw1 += bb*mb.z;
                aw2 += ba*ma.w;       aw2 += bb*mb.w;
                float cva0 = ca*ma.y, cva1 = ca*ma.z;
                float cvb0 = cb*mb.y, cvb1 = cb*mb.z;
                m00 += cva0*ma.y;     m00 += cvb0*mb.y;
                m01 += cva0*ma.z;     m01 += cvb0*mb.z;
                m02 += cva0*ma.w;     m02 += cvb0*mb.w;
                m11 += cva1*ma.z;     m11 += cvb1*mb.z;
                m12 += cva1*ma.w;     m12 += cvb1*mb.w;
                m22 += ca*ma.w*ma.w;  m22 += cb*mb.w*mb.w;
            }
            if (j < e1){
                int dst = dstA[j];
                float4 m4 = metaA[j];
                float s = pa + h2f(Pbh[(size_t)dst*HH + h]);
                const u32* Aa = attrSh + (size_t)j*16;
                float f1 = m4.x*fb1, f2 = m4.x*fb2, f3 = m4.x*fb3;
                #pragma unroll
                for (int q = 0; q < 16; ++q){
                    u32 a = Aa[q];
                    f1 = fdot2u(a, w1[q], f1);
                    f2 = fdot2u(a, w2[q], f2);
                    f3 = fdot2u(a, w3[q], f3);
                }
                float a = f1*s, b = f2*s, c = f3*s;
                ai  += a;
                aw0 += b*m4.y; aw1 += b*m4.z; aw2 += b*m4.w;
                float cv0 = c*m4.y, cv1 = c*m4.z;
                m00 += cv0*m4.y; m01 += cv0*m4.z; m02 += cv0*m4.w;
                m11 += cv1*m4.z; m12 += cv1*m4.w; m22 += c*m4.w*m4.w;
            }

            // X staging into Yl, tile-row layout (matches fragment preload)
            Yl[(0*16 + ni)*136 + h]     = f2h(ai);
            Yl[(16 + 3*ni + 0)*136 + h] = f2h(aw0);
            Yl[(16 + 3*ni + 1)*136 + h] = f2h(aw1);
            Yl[(16 + 3*ni + 2)*136 + h] = f2h(aw2);
            Yl[(64 + 6*ni + 0)*136 + h] = f2h(m00);
            Yl[(64 + 6*ni + 1)*136 + h] = f2h(m01);
            Yl[(64 + 6*ni + 2)*136 + h] = f2h(m02);
            Yl[(64 + 6*ni + 3)*136 + h] = f2h(m11);
            Yl[(64 + 6*ni + 4)*136 + h] = f2h(m12);
            Yl[(64 + 6*ni + 5)*136 + h] = f2h(m22);

            float tr3 = (m00 + m11 + m22) * (1.f/3.f);
            float x00 = ai + m00 - tr3, x11 = ai + m11 - tr3, x22 = ai + m22 - tr3;
            float nn = x00*x00 + x11*x11 + x22*x22
                     + 2.f*(m01*m01 + aw2*aw2 + m02*m02 + aw1*aw1 + m12*m12 + aw0*aw0);
            norm2l[ni][h] = nn;
        }
    }
    __syncthreads();

    // ---- preload mixing-GEMM A fragments from LDS X staging ----
    hf8 a0[4], a1[4];
    {
        int tile = wave;              // 0..7
        const u16* xr = &Yl[(tile*16 + rlo)*136 + kb*8];
        #pragma unroll
        for (int ks = 0; ks < 4; ++ks) a0[ks] = *(const hf8*)(xr + ks*32);
    }
    if (wave < 2){
        int tile = wave + 8;          // 8,9
        const u16* xr = &Yl[(tile*16 + rlo)*136 + kb*8];
        #pragma unroll
        for (int ks = 0; ks < 4; ++ks) a1[ks] = *(const hf8*)(xr + ks*32);
    }

    // ---- LN: waves 0..3 handle 4 nodes each, 16 lanes per node ----
    if (wave < 4){
        int ni = wave*4 + kb;
        float x[8]; float s = 0.f;
        #pragma unroll
        for (int k = 0; k < 8; ++k){ x[k] = norm2l[ni][rlo + 16*k]; s += x[k]; }
        #pragma unroll
        for (int d = 1; d < 16; d <<= 1) s += __shfl_xor(s, d);
        float mu = s * (1.f/HH);
        float q = 0.f;
        #pragma unroll
        for (int k = 0; k < 8; ++k){ float dx = x[k]-mu; q += dx*dx; }
        #pragma unroll
        for (int d = 1; d < 16; d <<= 1) q += __shfl_xor(q, d);
        float rs = rsqrtf(q*(1.f/HH) + LN_EPS);
        #pragma unroll
        for (int k = 0; k < 8; ++k){
            int h = rlo + 16*k;
            ysH[ni][h] = f2h((x[k]-mu)*rs*ln_g[h] + ln_b[h]);
        }
    }
    __syncthreads();   // frags in registers + ysH ready; Yl free to overwrite below

    // ---- ls1: Y1[16x256] = ys[16x128] @ W1^T, K=128; ct split over 8 waves ----
    {
        hf8 a[4];
        #pragma unroll
        for (int ks = 0; ks < 4; ++ks)
            a[ks] = *(const hf8*)&ysH[rlo][kb*8 + ks*32];
        for (int ct = wave; ct < 16; ct += 8){
            f32x4 acc = (f32x4){0.f,0.f,0.f,0.f};
            const u16* wr0 = ls1H + (size_t)(ct*16 + rlo)*HH;
            #pragma unroll
            for (int ks = 0; ks < 4; ++ks){
                hf8 bf = *(const hf8*)(wr0 + kb*8 + ks*32);
                acc = __builtin_amdgcn_mfma_f32_16x16x32_f16(a[ks], bf, acc, 0, 0, 0);
            }
            float bias = ls1_b[ct*16 + rlo];
            #pragma unroll
            for (int j = 0; j < 4; ++j)
                usH[kb*4 + j][ct*16 + rlo] = f2h(silu(acc[j] + bias));
        }
    }
    __syncthreads();

    // ---- ls2: Y2[16x384] = us[16x256] @ W2^T, K=256 -> gates (global, L2-resident) ----
    {
        hf8 a[8];
        #pragma unroll
        for (int ks = 0; ks < 8; ++ks)
            a[ks] = *(const hf8*)&usH[rlo][kb*8 + ks*32];
        for (int ct = wave; ct < 24; ct += 8){
            f32x4 acc = (f32x4){0.f,0.f,0.f,0.f};
            const u16* wr0 = ls2H + (size_t)(ct*16 + rlo)*256;
            #pragma unroll
            for (int ks = 0; ks < 8; ++ks){
                hf8 bf = *(const hf8*)(wr0 + kb*8 + ks*32);
                acc = __builtin_amdgcn_mfma_f32_16x16x32_f16(a[ks], bf, acc, 0, 0, 0);
            }
            float bias = ls2_b[ct*16 + rlo];
            #pragma unroll
            for (int j = 0; j < 4; ++j){
                int n = n0 + kb*4 + j;
                gates[(size_t)n*384 + ct*16 + rlo] = silu(acc[j] + bias);
            }
        }
    }

    // ---- mixing GEMMs: tile = wave (a0) and wave+8 for waves 0,1 (a1) ----
    {
        int tile = wave;
        const u16* W = (tile == 0) ? ltH : ((tile < 4) ? ltH + 16384 : ltH + 32768);
        #pragma unroll
        for (int ct = 0; ct < 8; ++ct){
            f32x4 acc = (f32x4){0.f,0.f,0.f,0.f};
            const hf8* wr = (const hf8*)(W + (size_t)(ct*16 + rlo)*HH + kb*8);
            #pragma unroll
            for (int ks = 0; ks < 4; ++ks)
                acc = __builtin_amdgcn_mfma_f32_16x16x32_f16(a0[ks], wr[ks*4], acc, 0, 0, 0);
            #pragma unroll
            for (int j = 0; j < 4; ++j)
                Yl[(tile*16 + kb*4 + j)*136 + ct*16 + rlo] = f2h(acc[j]);
        }
    }
    if (wave < 2){
        int tile = wave + 8;
        const u16* W = ltH + 32768;
        #pragma unroll
        for (int ct = 0; ct < 8; ++ct){
            f32x4 acc = (f32x4){0.f,0.f,0.f,0.f};
            const hf8* wr = (const hf8*)(W + (size_t)(ct*16 + rlo)*HH + kb*8);
            #pragma unroll
            for (int ks = 0; ks < 4; ++ks)
                acc = __builtin_amdgcn_mfma_f32_16x16x32_f16(a1[ks], wr[ks*4], acc, 0, 0, 0);
            #pragma unroll
            for (int j = 0; j < 4; ++j)
                Yl[(tile*16 + kb*4 + j)*136 + ct*16 + rlo] = f2h(acc[j]);
        }
    }
    __syncthreads();

    // ---- compose ----
    #pragma unroll
    for (int q = 0; q < 4; ++q){
        int id = q*512 + t;
        int ni = id >> 7, g = id & 127;
        int n = n0 + ni;
        float mi  = h2f(Yl[ni*136 + g]);
        float mw0 = h2f(Yl[(16 + 3*ni + 0)*136 + g]);
        float mw1 = h2f(Yl[(16 + 3*ni + 1)*136 + g]);
        float mw2 = h2f(Yl[(16 + 3*ni + 2)*136 + g]);
        float mm0 = h2f(Yl[(64 + 6*ni + 0)*136 + g]);
        float mm1 = h2f(Yl[(64 + 6*ni + 1)*136 + g]);
        float mm2 = h2f(Yl[(64 + 6*ni + 2)*136 + g]);
        float mm3 = h2f(Yl[(64 + 6*ni + 3)*136 + g]);
        float mm4 = h2f(Yl[(64 + 6*ni + 4)*136 + g]);
        float mm5 = h2f(Yl[(64 + 6*ni + 5)*136 + g]);
        float g0 = gates[(size_t)n*384 + 3*g];
        float g1 = gates[(size_t)n*384 + 3*g + 1];
        float g2 = gates[(size_t)n*384 + 3*g + 2];
        float t3 = (mm0 + mm3 + mm5) * (1.f/3.f);
        float* op = out + ((size_t)n*HH + g)*9;
        op[0] =  g0*mi  + g2*(mm0 - t3);
        op[1] = -g1*mw2 + g2*mm1;
        op[2] =  g1*mw1 + g2*mm2;
        op[3] =  g1*mw2 + g2*mm1;
        op[4] =  g0*mi  + g2*(mm3 - t3);
        op[5] = -g1*mw0 + g2*mm4;
        op[6] = -g1*mw1 + g2*mm2;
        op[7] =  g1*mw0 + g2*mm4;
        op[8] =  g0*mi  + g2*(mm5 - t3);
    }
}

extern "C" void kernel_launch(void* const* d_in, const int* in_sizes, int n_in,
                              void* d_out, int out_size, void* d_ws, size_t ws_size,
                              hipStream_t stream)
{
    float* out = (float*)d_out;
    int sig_blocks = (out_size + 255)/256;

    if (out_size != NN*HH*9){
        k_sig<<<sig_blocks, 256, 0, stream>>>(out, 400.f, out_size);
        return;
    }
    if (n_in != 30){
        k_sig<<<sig_blocks, 256, 0, stream>>>(out, 300.f + (float)n_in, out_size);
        return;
    }
    static const int want[30] = {
        4096, 131072, 65536, 196608, 2097152, 4096, 4096,
        16384, 32768, 128, 128, 128, 128, 32768, 128,
        4096, 128, 4096, 128, 4096, 128,
        16384, 16384, 16384, 32768, 256, 98304, 384, 128, 128
    };
    for (int i = 0; i < 30; ++i){
        if (in_sizes[i] != want[i]){
            k_sig<<<sig_blocks, 256, 0, stream>>>(out, 200.f + (float)i, out_size);
            return;
        }
    }

    const u8*    z_raw        = (const u8*)d_in[0];
    const u8*    ei_raw       = (const u8*)d_in[1];
    const float* edge_weight  = (const float*)d_in[2];
    const float* edge_vec     = (const float*)d_in[3];
    const float* edge_attr    = (const float*)d_in[4];
    const float* labels       = (const float*)d_in[5];
    const u8*    mask_raw     = (const u8*)d_in[6];
    const float* emb_w        = (const float*)d_in[7];
    const float* emb2_w       = (const float*)d_in[8];
    const float* emb2_b       = (const float*)d_in[9];
    const float* label_emb_w  = (const float*)d_in[10];
    const float* label_emb_b  = (const float*)d_in[11];
    const float* mask_token   = (const float*)d_in[12];
    const float* label_emb2_w = (const float*)d_in[13];
    const float* label_emb2_b = (const float*)d_in[14];
    const float* dp1_w = (const float*)d_in[15];
    const float* dp1_b = (const float*)d_in[16];
    const float* dp2_w = (const float*)d_in[17];
    const float* dp2_b = (const float*)d_in[18];
    const float* dp3_w = (const float*)d_in[19];
    const float* dp3_b = (const float*)d_in[20];
    const float* lt0_w = (const float*)d_in[21];
    const float* lt1_w = (const float*)d_in[22];
    const float* lt2_w = (const float*)d_in[23];
    const float* ls1_w = (const float*)d_in[24];
    const float* ls1_b = (const float*)d_in[25];
    const float* ls2_w = (const float*)d_in[26];
    const float* ls2_b = (const float*)d_in[27];
    const float* ln_g  = (const float*)d_in[28];
    const float* ln_b  = (const float*)d_in[29];

    char* ws = (char*)d_ws;
    size_t off = 0;
    auto alloc = [&](size_t bytes) -> void* {
        void* p = ws + off;
        off += (bytes + 255) & ~(size_t)255;
        return p;
    };
    float* Pa      = (float*)alloc((size_t)NN*HH*4);
    u16*   Pbh     = (u16*)alloc((size_t)NN*HH*2);
    float* gates   = (float*)alloc((size_t)NN*384*4);
    float* PzA     = (float*)alloc((size_t)MAXZ*HH*4);
    float* PzB     = (float*)alloc((size_t)MAXZ*HH*4);
    float* vecs    = (float*)alloc((size_t)6*HH*4);
    u32*   dpTh    = (u32*)alloc((size_t)3*16*HH*4);
    u16*   ls1H    = (u16*)alloc((size_t)32768*2);
    u16*   ls2H    = (u16*)alloc((size_t)98304*2);
    u16*   ltH     = (u16*)alloc((size_t)3*16384*2);
    u32*   attrSh  = (u32*)alloc((size_t)EE*16*4);
    float* metaA   = (float*)alloc((size_t)EE*16);
    int*   dstA    = (int*)alloc((size_t)EE*4);
    int*   z32     = (int*)alloc((size_t)NN*4);
    int*   ei32    = (int*)alloc((size_t)2*EE*4);
    int*   m32     = (int*)alloc((size_t)NN*4);
    int*   deg     = (int*)alloc((size_t)NN*4);
    int*   offsets = (int*)alloc((size_t)(NN+1)*4);
    int*   cursor  = (int*)alloc((size_t)NN*4);

    if (off > ws_size){
        k_sig<<<sig_blocks, 256, 0, stream>>>(out, 150.f, out_size);
        return;
    }

    k_zero   <<<NN/256, 256, 0, stream>>>(deg);
    k_cvt    <<<577, 256, 0, stream>>>(z_raw, ei_raw, mask_raw,
                                       z32, ei32, m32, deg,
                                       emb_w, emb2_w,
                                       label_emb_w, label_emb_b, mask_token,
                                       label_emb2_w, label_emb2_b, emb2_b,
                                       PzA, PzB, vecs);
    k_scan   <<<1, 256, 0, stream>>>(deg, offsets, cursor);
    k_sp     <<<3032, 256, 0, stream>>>(ei32, cursor, edge_weight, edge_vec,
                                        edge_attr, attrSh, dstA, (float4*)metaA,
                                        ls1_w, ls2_w, lt0_w, lt1_w, lt2_w,
                                        dp1_w, dp2_w, dp3_w,
                                        ls1H, ls2H, ltH, dpTh,
                                        z32, m32, labels, PzA, PzB, vecs,
                                        Pa, Pbh);
    k_gt     <<<NN/16, 512, 0, stream>>>(attrSh, dstA, (const float4*)metaA,
                                         dpTh, dp1_b, dp2_b, dp3_b,
                                         Pa, Pbh, offsets,
                                         ln_g, ln_b, ls1H, ls1_b,
                                         ls2H, ls2_b, gates, ltH, out);
}

// Round 10
// 88.420 us; speedup vs baseline: 1.2696x; 1.2696x over previous
//
#include <hip/hip_runtime.h>
#include <hip/hip_bf16.h>
#include <math.h>

#define NN 4096
#define EE 65536
#define HH 128
#define RR 32
#define MAXZ 128
#define CUT 4.5f
#define PI_OVER_CUT 0.6981317007977318f
#define LN_EPS 1e-5f

typedef unsigned short u16;
typedef unsigned int u32;
typedef unsigned char u8;
typedef _Float16 h2 __attribute__((ext_vector_type(2)));
typedef _Float16 hf8 __attribute__((ext_vector_type(8)));
typedef float f32x4 __attribute__((ext_vector_type(4)));

__device__ __forceinline__ float dot4(float4 a, float4 b){
    return a.x*b.x + a.y*b.y + a.z*b.z + a.w*b.w;
}
__device__ __forceinline__ float silu(float x){ return x / (1.f + __expf(-x)); }
__device__ __forceinline__ u32 packh2(float a, float b){
    union{u32 u; h2 h;} v; v.h = (h2){(_Float16)a, (_Float16)b}; return v.u;
}
__device__ __forceinline__ float fdot2u(u32 a, u32 b, float c){
    union{u32 u; h2 h;} x, y; x.u = a; y.u = b;
    return __builtin_amdgcn_fdot2(x.h, y.h, c, false);
}
__device__ __forceinline__ u16 f2h(float f){
    union{u16 u; _Float16 h;} v; v.h = (_Float16)f; return v.u;
}
__device__ __forceinline__ float h2f(u16 u){
    union{u16 u_; _Float16 h;} v; v.u_ = u; return (float)v.h;
}

// ---------------- diagnostic signal (f32) ----------------
__global__ void k_sig(float* __restrict__ out, float val, int n){
    int i = blockIdx.x*256 + threadIdx.x;
    if (i < n) out[i] = val;
}

// ---------------- zero deg ----------------
__global__ void k_zero(int* __restrict__ deg){
    deg[blockIdx.x*256 + threadIdx.x] = 0;
}

// ---------------- convert+histogram (512) + Pz GEMM (64) + label vecs (1) ----------------
__global__ __launch_bounds__(256) void k_cvt(const u8* __restrict__ zr,
                                             const u8* __restrict__ eir,
                                             const u8* __restrict__ mr,
                                             int* __restrict__ z32,
                                             int* __restrict__ ei32,
                                             int* __restrict__ m32,
                                             int* __restrict__ deg,
                                             const float* __restrict__ emb_w,
                                             const float* __restrict__ emb2_w,
                                             const float* __restrict__ label_emb_w,
                                             const float* __restrict__ label_emb_b,
                                             const float* __restrict__ mask_token,
                                             const float* __restrict__ label_emb2_w,
                                             const float* __restrict__ label_emb2_b,
                                             const float* __restrict__ emb2_b,
                                             float* __restrict__ PzA,
                                             float* __restrict__ PzB,
                                             float* __restrict__ vecs){
    int b = blockIdx.x, t = threadIdx.x;
    if (b < 512){
        __shared__ int sF1, sF3, sOdd, sZ64, sE64;
        if (t == 0){ sF1=0; sF3=0; sOdd=0; sZ64=1; sE64=1; }
        __syncthreads();
        for (int i = t; i < 4096; i += 256){
            u8 bb = mr[i];
            if ((i & 3) == 1 && bb == 0x3F) sF1 = 1;
            if ((i & 3) == 3 && bb == 0x3F) sF3 = 1;
            if ((i & 3) != 0 && bb != 0)    sOdd = 1;
        }
        const u32* zw = (const u32*)zr;
        const u32* ew = (const u32*)eir;
        for (int i = t; i < 128; i += 256) if (zw[2*i + 1]) sZ64 = 0;
        for (int i = t; i < 512; i += 256) if (ew[2*i + 1]) sE64 = 0;
        __syncthreads();
        int mf = sF1 ? 2 : (sF3 ? 0 : (sOdd ? 1 : 0));
        int z64 = sZ64, e64 = sE64;

        int i = b*256 + t;
        if (i < NN){
            z32[i] = z64 ? ((const int*)zr)[2*i] : ((const int*)zr)[i];
            int mm;
            if (mf == 1)      mm = (mr[i] != 0);
            else if (mf == 2) mm = (((const u16*)mr)[i] != 0);
            else              mm = (((const u32*)mr)[i] != 0u);
            m32[i] = mm;
        }
        if (i < 2*EE){
            int v = e64 ? ((const int*)eir)[2*i] : ((const int*)eir)[i];
            ei32[i] = v;
            if (i < EE) atomicAdd(&deg[v], 1);
        }
        return;
    }
    if (b < 576){
        int zi = (b - 512)*2 + (t >> 7), h = t & 127;
        __shared__ float Zs[2][HH];
        Zs[t >> 7][h] = emb_w[zi*HH + h];
        __syncthreads();
        const float4* wa = (const float4*)(emb2_w + h*2*HH);
        const float4* wb = (const float4*)(emb2_w + h*2*HH + HH);
        float pa = 0.f, pbv = 0.f;
        const float* Z = Zs[t >> 7];
        #pragma unroll 8
        for (int j = 0; j < HH/4; ++j){
            float4 zp = *(const float4*)&Z[4*j];
            pa  += dot4(wa[j], zp);
            pbv += dot4(wb[j], zp);
        }
        PzA[zi*HH + h] = pa;
        PzB[zi*HH + h] = pbv;
        return;
    }
    if (t < 128){
        int h = t;
        const float* wa = label_emb2_w + h*2*HH;
        const float* wb = wa + HH;
        float uA=0.f,vA=0.f,wA=0.f,uB=0.f,vB=0.f,wB=0.f;
        for (int j = 0; j < HH; ++j){
            float a = wa[j], bb = wb[j];
            float u = label_emb_w[j], v = label_emb_b[j], m = mask_token[j];
            uA += a*u; vA += a*v; wA += a*m;
            uB += bb*u; vB += bb*v; wB += bb*m;
        }
        float bias = emb2_b[h] + label_emb2_b[h];
        vecs[0*HH + h] = uA;
        vecs[1*HH + h] = vA + bias;
        vecs[2*HH + h] = wA + bias;
        vecs[3*HH + h] = uB;
        vecs[4*HH + h] = vB;
        vecs[5*HH + h] = wB;
    }
}

// ---------------- block scan of degrees ----------------
__global__ __launch_bounds__(256) void k_scan(const int* __restrict__ deg,
                                              int* __restrict__ offsets,
                                              int* __restrict__ cursor){
    int t = threadIdx.x;
    int lane = t & 63, wid = t >> 6;
    int4 d[4];
    #pragma unroll
    for (int q = 0; q < 4; ++q) d[q] = ((const int4*)deg)[t*4 + q];
    int vals[16];
    #pragma unroll
    for (int q = 0; q < 4; ++q){
        vals[4*q+0]=d[q].x; vals[4*q+1]=d[q].y; vals[4*q+2]=d[q].z; vals[4*q+3]=d[q].w;
    }
    int sum = 0;
    #pragma unroll
    for (int q = 0; q < 16; ++q) sum += vals[q];
    int incl = sum;
    #pragma unroll
    for (int dd = 1; dd < 64; dd <<= 1){ int s = __shfl_up(incl, dd); if (lane >= dd) incl += s; }
    __shared__ int wsum[4];
    if (lane == 63) wsum[wid] = incl;
    __syncthreads();
    int base = 0;
    for (int w = 0; w < wid; ++w) base += wsum[w];
    int run = base + incl - sum;
    #pragma unroll
    for (int q = 0; q < 16; ++q){
        offsets[t*16 + q] = run;
        cursor [t*16 + q] = run;
        run += vals[q];
    }
    if (t == 255) offsets[NN] = run;
}

// ---------------- fused: scatter+edge-meta (256) + weight casts (728) + combine (2048) ----------------
__global__ __launch_bounds__(256) void k_sp(
    const int* __restrict__ ei, int* __restrict__ cursor,
    const float* __restrict__ ew, const float* __restrict__ ev,
    const float* __restrict__ ea,
    u32* __restrict__ attrSh, int* __restrict__ dstA, float4* __restrict__ metaA,
    const float* __restrict__ ls1_w, const float* __restrict__ ls2_w,
    const float* __restrict__ lt0_w, const float* __restrict__ lt1_w,
    const float* __restrict__ lt2_w,
    const float* __restrict__ dp1_w, const float* __restrict__ dp2_w,
    const float* __restrict__ dp3_w,
    u16* __restrict__ ls1H, u16* __restrict__ ls2H, u16* __restrict__ ltH,
    u32* __restrict__ dpTh,
    const int* __restrict__ z32, const int* __restrict__ m32,
    const float* __restrict__ labels,
    const float* __restrict__ PzA, const float* __restrict__ PzB,
    const float* __restrict__ vecs,
    float* __restrict__ Pa, u16* __restrict__ Pbh)
{
    int b = blockIdx.x, t = threadIdx.x;
    if (b < 256){
        int e = b*256 + t;
        int s = ei[e];
        int p = atomicAdd(&cursor[s], 1);
        float d = ew[e];
        float cutv = (d < CUT) ? 0.5f*(__cosf(d*PI_OVER_CUT) + 1.f) : 0.f;
        dstA[p] = ei[EE + e];
        metaA[p] = make_float4(cutv, ev[3*e], ev[3*e+1], ev[3*e+2]);
        const float* a = ea + (size_t)e*RR;
        u32* o = attrSh + (size_t)p*16;
        #pragma unroll
        for (int q = 0; q < 16; ++q)
            o[q] = packh2(cutv*a[2*q], cutv*a[2*q+1]);
        return;
    }
    int pb = b - 256;
    if (pb < 728){
        int i = pb*256 + t;
        if (i < 32768){ ls1H[i] = f2h(ls1_w[i]); return; }
        i -= 32768;
        if (i < 98304){ ls2H[i] = f2h(ls2_w[i]); return; }
        i -= 98304;
        if (i < 16384){ ltH[0*16384 + i] = f2h(lt0_w[i]); return; }
        i -= 16384;
        if (i < 16384){ ltH[1*16384 + i] = f2h(lt1_w[i]); return; }
        i -= 16384;
        if (i < 16384){ ltH[2*16384 + i] = f2h(lt2_w[i]); return; }
        i -= 16384;
        if (i < 6144){
            int j = i >> 11, rem = i & 2047, q = rem >> 7, h = rem & 127;
            const float* src = (j == 0) ? dp1_w : ((j == 1) ? dp2_w : dp3_w);
            dpTh[(j*16 + q)*HH + h] = packh2(src[h*RR + 2*q], src[h*RR + 2*q + 1]);
            return;
        }
        return;
    }
    // ---- combine into Pa (f32) / Pbh (fp16): 2048 blocks ----
    int i = (b - 984)*256 + t;
    int n = i >> 7, h = i & 127;
    int zi = z32[n];
    int mk = m32[n];
    float lab = labels[n];
    float la = mk ? vecs[2*HH + h] : lab*vecs[0*HH + h] + vecs[1*HH + h];
    float lb = mk ? vecs[5*HH + h] : lab*vecs[3*HH + h] + vecs[4*HH + h];
    Pa[i]  = PzA[zi*HH + h] + la;
    Pbh[i] = f2h(PzB[zi*HH + h] + lb);
}

// ---------------- main per-node gather (fp16 dot2, unroll-2, fp16 GEMM-row output) ----------------
__global__ __launch_bounds__(128) void k_gather(
    const u32* __restrict__ attrSh, const int* __restrict__ dstA,
    const float4* __restrict__ metaA,
    const u32* __restrict__ dpTh,
    const float* __restrict__ dp1_b, const float* __restrict__ dp2_b,
    const float* __restrict__ dp3_b,
    const float* __restrict__ Pa, const u16* __restrict__ Pbh,
    const int* __restrict__ offsets,
    u16* __restrict__ X0, u16* __restrict__ X1, u16* __restrict__ X2,
    float* __restrict__ norm2)
{
    int n = blockIdx.x, t = threadIdx.x;
    u32 w1[16], w2[16], w3[16];
    #pragma unroll
    for (int q = 0; q < 16; ++q){
        w1[q] = dpTh[(0*16 + q)*HH + t];
        w2[q] = dpTh[(1*16 + q)*HH + t];
        w3[q] = dpTh[(2*16 + q)*HH + t];
    }
    float fb1 = dp1_b[t], fb2 = dp2_b[t], fb3 = dp3_b[t];
    float pa = Pa[n*HH + t];
    float ai = 0.f, aw0 = 0.f, aw1 = 0.f, aw2 = 0.f;
    float m00 = 0.f, m01 = 0.f, m02 = 0.f, m11 = 0.f, m12 = 0.f, m22 = 0.f;

    int e0 = offsets[n], e1 = offsets[n+1];
    int j = e0;
    for (; j + 1 < e1; j += 2){
        int dsta = dstA[j], dstb = dstA[j+1];
        float4 ma = metaA[j], mb = metaA[j+1];
        float sa = pa + h2f(Pbh[(size_t)dsta*HH + t]);
        float sb = pa + h2f(Pbh[(size_t)dstb*HH + t]);
        const u32* Aa = attrSh + (size_t)j*16;
        const u32* Ab = Aa + 16;
        float f1a = ma.x*fb1, f2a = ma.x*fb2, f3a = ma.x*fb3;
        float f1b = mb.x*fb1, f2b = mb.x*fb2, f3b = mb.x*fb3;
        #pragma unroll
        for (int q = 0; q < 16; ++q){
            u32 a = Aa[q], bq = Ab[q];
            f1a = fdot2u(a, w1[q], f1a);
            f2a = fdot2u(a, w2[q], f2a);
            f3a = fdot2u(a, w3[q], f3a);
            f1b = fdot2u(bq, w1[q], f1b);
            f2b = fdot2u(bq, w2[q], f2b);
            f3b = fdot2u(bq, w3[q], f3b);
        }
        float aa = f1a*sa, ba = f2a*sa, ca = f3a*sa;
        float ab = f1b*sb, bb = f2b*sb, cb = f3b*sb;
        ai  += aa;            ai  += ab;
        aw0 += ba*ma.y;       aw0 += bb*mb.y;
        aw1 += ba*ma.z;       aw1 += bb*mb.z;
        aw2 += ba*ma.w;       aw2 += bb*mb.w;
        float cva0 = ca*ma.y, cva1 = ca*ma.z;
        float cvb0 = cb*mb.y, cvb1 = cb*mb.z;
        m00 += cva0*ma.y;     m00 += cvb0*mb.y;
        m01 += cva0*ma.z;     m01 += cvb0*mb.z;
        m02 += cva0*ma.w;     m02 += cvb0*mb.w;
        m11 += cva1*ma.z;     m11 += cvb1*mb.z;
        m12 += cva1*ma.w;     m12 += cvb1*mb.w;
        m22 += ca*ma.w*ma.w;  m22 += cb*mb.w*mb.w;
    }
    if (j < e1){
        int dst = dstA[j];
        float4 m4 = metaA[j];
        float s = pa + h2f(Pbh[(size_t)dst*HH + t]);
        const u32* Aa = attrSh + (size_t)j*16;
        float f1 = m4.x*fb1, f2 = m4.x*fb2, f3 = m4.x*fb3;
        #pragma unroll
        for (int q = 0; q < 16; ++q){
            u32 a = Aa[q];
            f1 = fdot2u(a, w1[q], f1);
            f2 = fdot2u(a, w2[q], f2);
            f3 = fdot2u(a, w3[q], f3);
        }
        float a = f1*s, b = f2*s, c = f3*s;
        ai  += a;
        aw0 += b*m4.y; aw1 += b*m4.z; aw2 += b*m4.w;
        float cv0 = c*m4.y, cv1 = c*m4.z;
        m00 += cv0*m4.y; m01 += cv0*m4.z; m02 += cv0*m4.w;
        m11 += cv1*m4.z; m12 += cv1*m4.w; m22 += c*m4.w*m4.w;
    }

    X0[(size_t)n*HH + t] = f2h(ai);
    u16* x1p = X1 + (size_t)3*n*HH + t;
    x1p[0*HH] = f2h(aw0); x1p[1*HH] = f2h(aw1); x1p[2*HH] = f2h(aw2);
    u16* x2p = X2 + (size_t)6*n*HH + t;
    x2p[0*HH] = f2h(m00); x2p[1*HH] = f2h(m01); x2p[2*HH] = f2h(m02);
    x2p[3*HH] = f2h(m11); x2p[4*HH] = f2h(m12); x2p[5*HH] = f2h(m22);

    float tr3 = (m00 + m11 + m22) * (1.f/3.f);
    float x00 = ai + m00 - tr3, x11 = ai + m11 - tr3, x22 = ai + m22 - tr3;
    float nn = x00*x00 + x11*x11 + x22*x22
             + 2.f*(m01*m01 + aw2*aw2 + m02*m02 + aw1*aw1 + m12*m12 + aw0*aw0);
    norm2[n*HH + t] = nn;
}

// ---------------- fused tail: LN + gate MLP + mixing GEMMs + compose (8 waves) ----------------
__global__ __launch_bounds__(512) void k_tail(
    const float* __restrict__ norm2, const float* __restrict__ ln_g,
    const float* __restrict__ ln_b,
    const u16* __restrict__ ls1H, const float* __restrict__ ls1_b,
    const u16* __restrict__ ls2H, const float* __restrict__ ls2_b,
    float* __restrict__ gates,
    const u16* __restrict__ X0, const u16* __restrict__ X1,
    const u16* __restrict__ X2, const u16* __restrict__ ltH,
    float* __restrict__ out)
{
    int n0 = blockIdx.x * 16;
    int t = threadIdx.x;
    int wave = t >> 6, lane = t & 63;
    int rlo = lane & 15, kb = lane >> 4;
    __shared__ u16 ysH[16][136];
    __shared__ u16 usH[16][264];
    __shared__ u16 Yl[160*136];

    // ---- preload mixing-GEMM A fragments (independent of the MLP phase) ----
    hf8 a0[4], a1[4];
    {
        int tile = wave;              // 0..7
        const u16* X; int rbase;
        if (tile == 0)     { X = X0; rbase = n0; }
        else if (tile < 4) { X = X1; rbase = 3*n0 + (tile-1)*16; }
        else               { X = X2; rbase = 6*n0 + (tile-4)*16; }
        const hf8* xr = (const hf8*)(X + (size_t)(rbase + rlo)*HH + kb*8);
        #pragma unroll
        for (int ks = 0; ks < 4; ++ks) a0[ks] = xr[ks*4];
    }
    if (wave < 2){
        int tile = wave + 8;          // 8,9 -> X2
        int rbase = 6*n0 + (tile-4)*16;
        const hf8* xr = (const hf8*)(X2 + (size_t)(rbase + rlo)*HH + kb*8);
        #pragma unroll
        for (int ks = 0; ks < 4; ++ks) a1[ks] = xr[ks*4];
    }

    // ---- LN: waves 0..3 handle 4 nodes each, 16 lanes per node ----
    if (wave < 4){
        int ni = wave*4 + kb;
        int n = n0 + ni;
        float x[8]; float s = 0.f;
        #pragma unroll
        for (int k = 0; k < 8; ++k){ x[k] = norm2[(size_t)n*HH + rlo + 16*k]; s += x[k]; }
        #pragma unroll
        for (int d = 1; d < 16; d <<= 1) s += __shfl_xor(s, d);
        float mu = s * (1.f/HH);
        float q = 0.f;
        #pragma unroll
        for (int k = 0; k < 8; ++k){ float dx = x[k]-mu; q += dx*dx; }
        #pragma unroll
        for (int d = 1; d < 16; d <<= 1) q += __shfl_xor(q, d);
        float rs = rsqrtf(q*(1.f/HH) + LN_EPS);
        #pragma unroll
        for (int k = 0; k < 8; ++k){
            int h = rlo + 16*k;
            ysH[ni][h] = f2h((x[k]-mu)*rs*ln_g[h] + ln_b[h]);
        }
    }
    __syncthreads();

    // ---- ls1: Y1[16x256] = ys[16x128] @ W1^T, K=128; ct split over 8 waves ----
    {
        hf8 a[4];
        #pragma unroll
        for (int ks = 0; ks < 4; ++ks)
            a[ks] = *(const hf8*)&ysH[rlo][kb*8 + ks*32];
        for (int ct = wave; ct < 16; ct += 8){
            f32x4 acc = (f32x4){0.f,0.f,0.f,0.f};
            const u16* wr0 = ls1H + (size_t)(ct*16 + rlo)*HH;
            #pragma unroll
            for (int ks = 0; ks < 4; ++ks){
                hf8 bf = *(const hf8*)(wr0 + kb*8 + ks*32);
                acc = __builtin_amdgcn_mfma_f32_16x16x32_f16(a[ks], bf, acc, 0, 0, 0);
            }
            float bias = ls1_b[ct*16 + rlo];
            #pragma unroll
            for (int j = 0; j < 4; ++j)
                usH[kb*4 + j][ct*16 + rlo] = f2h(silu(acc[j] + bias));
        }
    }
    __syncthreads();

    // ---- ls2: Y2[16x384] = us[16x256] @ W2^T, K=256 -> gates (global, L2-resident) ----
    {
        hf8 a[8];
        #pragma unroll
        for (int ks = 0; ks < 8; ++ks)
            a[ks] = *(const hf8*)&usH[rlo][kb*8 + ks*32];
        for (int ct = wave; ct < 24; ct += 8){
            f32x4 acc = (f32x4){0.f,0.f,0.f,0.f};
            const u16* wr0 = ls2H + (size_t)(ct*16 + rlo)*256;
            #pragma unroll
            for (int ks = 0; ks < 8; ++ks){
                hf8 bf = *(const hf8*)(wr0 + kb*8 + ks*32);
                acc = __builtin_amdgcn_mfma_f32_16x16x32_f16(a[ks], bf, acc, 0, 0, 0);
            }
            float bias = ls2_b[ct*16 + rlo];
            #pragma unroll
            for (int j = 0; j < 4; ++j){
                int n = n0 + kb*4 + j;
                gates[(size_t)n*384 + ct*16 + rlo] = silu(acc[j] + bias);
            }
        }
    }
    // Yl is disjoint from ysH/usH; gates are read only after the post-GEMM
    // __syncthreads (which drains vmem before s_barrier).

    // ---- mixing GEMMs: tile = wave (a0) and wave+8 for waves 0,1 (a1) ----
    {
        int tile = wave;
        const u16* W = (tile == 0) ? ltH : ((tile < 4) ? ltH + 16384 : ltH + 32768);
        #pragma unroll
        for (int ct = 0; ct < 8; ++ct){
            f32x4 acc = (f32x4){0.f,0.f,0.f,0.f};
            const hf8* wr = (const hf8*)(W + (size_t)(ct*16 + rlo)*HH + kb*8);
            #pragma unroll
            for (int ks = 0; ks < 4; ++ks)
                acc = __builtin_amdgcn_mfma_f32_16x16x32_f16(a0[ks], wr[ks*4], acc, 0, 0, 0);
            #pragma unroll
            for (int j = 0; j < 4; ++j)
                Yl[(tile*16 + kb*4 + j)*136 + ct*16 + rlo] = f2h(acc[j]);
        }
    }
    if (wave < 2){
        int tile = wave + 8;
        const u16* W = ltH + 32768;
        #pragma unroll
        for (int ct = 0; ct < 8; ++ct){
            f32x4 acc = (f32x4){0.f,0.f,0.f,0.f};
            const hf8* wr = (const hf8*)(W + (size_t)(ct*16 + rlo)*HH + kb*8);
            #pragma unroll
            for (int ks = 0; ks < 4; ++ks)
                acc = __builtin_amdgcn_mfma_f32_16x16x32_f16(a1[ks], wr[ks*4], acc, 0, 0, 0);
            #pragma unroll
            for (int j = 0; j < 4; ++j)
                Yl[(tile*16 + kb*4 + j)*136 + ct*16 + rlo] = f2h(acc[j]);
        }
    }
    __syncthreads();

    // ---- compose ----
    #pragma unroll
    for (int q = 0; q < 4; ++q){
        int id = q*512 + t;
        int ni = id >> 7, g = id & 127;
        int n = n0 + ni;
        float mi  = h2f(Yl[ni*136 + g]);
        float mw0 = h2f(Yl[(16 + 3*ni + 0)*136 + g]);
        float mw1 = h2f(Yl[(16 + 3*ni + 1)*136 + g]);
        float mw2 = h2f(Yl[(16 + 3*ni + 2)*136 + g]);
        float mm0 = h2f(Yl[(64 + 6*ni + 0)*136 + g]);
        float mm1 = h2f(Yl[(64 + 6*ni + 1)*136 + g]);
        float mm2 = h2f(Yl[(64 + 6*ni + 2)*136 + g]);
        float mm3 = h2f(Yl[(64 + 6*ni + 3)*136 + g]);
        float mm4 = h2f(Yl[(64 + 6*ni + 4)*136 + g]);
        float mm5 = h2f(Yl[(64 + 6*ni + 5)*136 + g]);
        float g0 = gates[(size_t)n*384 + 3*g];
        float g1 = gates[(size_t)n*384 + 3*g + 1];
        float g2 = gates[(size_t)n*384 + 3*g + 2];
        float t3 = (mm0 + mm3 + mm5) * (1.f/3.f);
        float* op = out + ((size_t)n*HH + g)*9;
        op[0] =  g0*mi  + g2*(mm0 - t3);
        op[1] = -g1*mw2 + g2*mm1;
        op[2] =  g1*mw1 + g2*mm2;
        op[3] =  g1*mw2 + g2*mm1;
        op[4] =  g0*mi  + g2*(mm3 - t3);
        op[5] = -g1*mw0 + g2*mm4;
        op[6] = -g1*mw1 + g2*mm2;
        op[7] =  g1*mw0 + g2*mm4;
        op[8] =  g0*mi  + g2*(mm5 - t3);
    }
}

extern "C" void kernel_launch(void* const* d_in, const int* in_sizes, int n_in,
                              void* d_out, int out_size, void* d_ws, size_t ws_size,
                              hipStream_t stream)
{
    float* out = (float*)d_out;
    int sig_blocks = (out_size + 255)/256;

    if (out_size != NN*HH*9){
        k_sig<<<sig_blocks, 256, 0, stream>>>(out, 400.f, out_size);
        return;
    }
    if (n_in != 30){
        k_sig<<<sig_blocks, 256, 0, stream>>>(out, 300.f + (float)n_in, out_size);
        return;
    }
    static const int want[30] = {
        4096, 131072, 65536, 196608, 2097152, 4096, 4096,
        16384, 32768, 128, 128, 128, 128, 32768, 128,
        4096, 128, 4096, 128, 4096, 128,
        16384, 16384, 16384, 32768, 256, 98304, 384, 128, 128
    };
    for (int i = 0; i < 30; ++i){
        if (in_sizes[i] != want[i]){
            k_sig<<<sig_blocks, 256, 0, stream>>>(out, 200.f + (float)i, out_size);
            return;
        }
    }

    const u8*    z_raw        = (const u8*)d_in[0];
    const u8*    ei_raw       = (const u8*)d_in[1];
    const float* edge_weight  = (const float*)d_in[2];
    const float* edge_vec     = (const float*)d_in[3];
    const float* edge_attr    = (const float*)d_in[4];
    const float* labels       = (const float*)d_in[5];
    const u8*    mask_raw     = (const u8*)d_in[6];
    const float* emb_w        = (const float*)d_in[7];
    const float* emb2_w       = (const float*)d_in[8];
    const float* emb2_b       = (const float*)d_in[9];
    const float* label_emb_w  = (const float*)d_in[10];
    const float* label_emb_b  = (const float*)d_in[11];
    const float* mask_token   = (const float*)d_in[12];
    const float* label_emb2_w = (const float*)d_in[13];
    const float* label_emb2_b = (const float*)d_in[14];
    const float* dp1_w = (const float*)d_in[15];
    const float* dp1_b = (const float*)d_in[16];
    const float* dp2_w = (const float*)d_in[17];
    const float* dp2_b = (const float*)d_in[18];
    const float* dp3_w = (const float*)d_in[19];
    const float* dp3_b = (const float*)d_in[20];
    const float* lt0_w = (const float*)d_in[21];
    const float* lt1_w = (const float*)d_in[22];
    const float* lt2_w = (const float*)d_in[23];
    const float* ls1_w = (const float*)d_in[24];
    const float* ls1_b = (const float*)d_in[25];
    const float* ls2_w = (const float*)d_in[26];
    const float* ls2_b = (const float*)d_in[27];
    const float* ln_g  = (const float*)d_in[28];
    const float* ln_b  = (const float*)d_in[29];

    char* ws = (char*)d_ws;
    size_t off = 0;
    auto alloc = [&](size_t bytes) -> void* {
        void* p = ws + off;
        off += (bytes + 255) & ~(size_t)255;
        return p;
    };
    float* Pa      = (float*)alloc((size_t)NN*HH*4);
    u16*   Pbh     = (u16*)alloc((size_t)NN*HH*2);
    float* norm2   = (float*)alloc((size_t)NN*HH*4);
    float* gates   = (float*)alloc((size_t)NN*384*4);
    float* PzA     = (float*)alloc((size_t)MAXZ*HH*4);
    float* PzB     = (float*)alloc((size_t)MAXZ*HH*4);
    float* vecs    = (float*)alloc((size_t)6*HH*4);
    u32*   dpTh    = (u32*)alloc((size_t)3*16*HH*4);
    u16*   ls1H    = (u16*)alloc((size_t)32768*2);
    u16*   ls2H    = (u16*)alloc((size_t)98304*2);
    u16*   ltH     = (u16*)alloc((size_t)3*16384*2);
    u16*   X0      = (u16*)alloc((size_t)NN*HH*2);
    u16*   X1      = (u16*)alloc((size_t)3*NN*HH*2);
    u16*   X2      = (u16*)alloc((size_t)6*NN*HH*2);
    u32*   attrSh  = (u32*)alloc((size_t)EE*16*4);
    float* metaA   = (float*)alloc((size_t)EE*16);
    int*   dstA    = (int*)alloc((size_t)EE*4);
    int*   z32     = (int*)alloc((size_t)NN*4);
    int*   ei32    = (int*)alloc((size_t)2*EE*4);
    int*   m32     = (int*)alloc((size_t)NN*4);
    int*   deg     = (int*)alloc((size_t)NN*4);
    int*   offsets = (int*)alloc((size_t)(NN+1)*4);
    int*   cursor  = (int*)alloc((size_t)NN*4);

    if (off > ws_size){
        k_sig<<<sig_blocks, 256, 0, stream>>>(out, 150.f, out_size);
        return;
    }

    k_zero   <<<NN/256, 256, 0, stream>>>(deg);
    k_cvt    <<<577, 256, 0, stream>>>(z_raw, ei_raw, mask_raw,
                                       z32, ei32, m32, deg,
                                       emb_w, emb2_w,
                                       label_emb_w, label_emb_b, mask_token,
                                       label_emb2_w, label_emb2_b, emb2_b,
                                       PzA, PzB, vecs);
    k_scan   <<<1, 256, 0, stream>>>(deg, offsets, cursor);
    k_sp     <<<3032, 256, 0, stream>>>(ei32, cursor, edge_weight, edge_vec,
                                        edge_attr, attrSh, dstA, (float4*)metaA,
                                        ls1_w, ls2_w, lt0_w, lt1_w, lt2_w,
                                        dp1_w, dp2_w, dp3_w,
                                        ls1H, ls2H, ltH, dpTh,
                                        z32, m32, labels, PzA, PzB, vecs,
                                        Pa, Pbh);
    k_gather <<<NN, 128, 0, stream>>>(attrSh, dstA, (const float4*)metaA,
                                      dpTh, dp1_b, dp2_b, dp3_b,
                                      Pa, Pbh, offsets, X0, X1, X2, norm2);
    k_tail   <<<NN/16, 512, 0, stream>>>(norm2, ln_g, ln_b, ls1H, ls1_b,
                                         ls2H, ls2_b, gates,
                                         X0, X1, X2, ltH, out);
}